// Round 6
// baseline (196.590 us; speedup 1.0000x reference)
//
#include <hip/hip_runtime.h>

#define N_RAYS 65536
#define N_PTS  128
#define FAR_DELTA 1e10f

#define BLOCK   256
#define NBLOCKS 2048                          // 8 blocks/CU, no LDS -> 32 waves/CU
#define NWAVES  (NBLOCKS * (BLOCK / 64))      // 8192 waves
#define NPAIRS  (N_RAYS / 2)                  // 32768 ray-pairs
#define NP      (NPAIRS / NWAVES)             // 4 pairs per wave

typedef float f32x4 __attribute__((ext_vector_type(4)));

// DPP cross-lane on the VALU pipe (round-5 verified math).
#define ROW_SHR(n)  (0x110 | (n))
#define ROW_SHL(n)  (0x100 | (n))
#define ROW_BCAST15 0x142

template<int CTRL, int RMASK, bool BC>
__device__ __forceinline__ float dpp_f(float x) {
    return __builtin_bit_cast(float,
        __builtin_amdgcn_update_dpp(0, __builtin_bit_cast(int, x),
                                    CTRL, RMASK, 0xF, BC));
}

// Register pipeline the compiler cannot delete (round 3's failure mode):
// volatile asm global loads into named VGPRs, counted vmcnt, sched_barrier
// after each wait (guide rule #18: hipcc hoists register-only ops past
// inline-asm waitcnt otherwise).
__global__ __launch_bounds__(BLOCK) void volrend_kernel(
    const float* __restrict__ depth,
    const float* __restrict__ density,
    const float* __restrict__ feature,
    float* __restrict__ out)
{
    const int lane = threadIdx.x & 63;
    const int sl   = lane & 31;               // lane within 32-lane ray segment
    const int g    = (int)blockIdx.x * (BLOCK / 64) + (threadIdx.x >> 6);

    f32x4 d, rho, f0, f1, f2;  float nx;      // current pair (21 VGPRs)
    f32x4 pd, pr, pf0, pf1, pf2; float pnx;   // prefetched next pair

#define GLD4(dst_, gp_) \
    asm volatile("global_load_dwordx4 %0, %1, off" : "=v"(dst_) : "v"(gp_))
#define GLD1(dst_, gp_) \
    asm volatile("global_load_dword %0, %1, off"   : "=v"(dst_) : "v"(gp_))

    // 6 loads per pair, all wave-contiguous (16 B/lane; nx overlaps d's lines,
    // L1-served). Lane sl==31's nx is unused (sentinel) -> clamp its address
    // in-bounds for the last pair.
#define ISSUE(p_, D_, R_, F0_, F1_, F2_, NX_)                                 \
    do {                                                                      \
        const float* dp_ = depth + (size_t)(p_) * 256 + 4 * lane;             \
        GLD4(D_, dp_);                                                        \
        GLD1(NX_, dp_ + ((sl == 31) ? 3 : 4));                                \
        GLD4(R_, density + (size_t)(p_) * 256 + 4 * lane);                    \
        const float* fp_ = feature + (size_t)(p_) * 768 + 12 * lane;          \
        GLD4(F0_, fp_);                                                       \
        GLD4(F1_, fp_ + 4);                                                   \
        GLD4(F2_, fp_ + 8);                                                   \
    } while (0)

    ISSUE(g, d, rho, f0, f1, f2, nx);

#pragma unroll
    for (int p = 0; p < NP; ++p) {
        if (p + 1 < NP)
            ISSUE((p + 1) * NWAVES + g, pd, pr, pf0, pf1, pf2, pnx);

        // vmcnt ledger (6 loads L, 1 store S per pair, issue order):
        // p=0: [L0 L1]=12, drain L0 -> 6
        // p=1: [L1 S0 L2]=13, drain L1 -> 7
        // p=2: [S0 L2 S1 L3]=14, drain S0+L2 -> 7
        // p=3: [S1 L3 S2]=8, drain S1+L3 -> 1
        if      (p == 0)      asm volatile("s_waitcnt vmcnt(6)" ::: "memory");
        else if (p <  NP - 1) asm volatile("s_waitcnt vmcnt(7)" ::: "memory");
        else                  asm volatile("s_waitcnt vmcnt(1)" ::: "memory");
        __builtin_amdgcn_sched_barrier(0);

        // ---- taus + in-register local prefix (round-5 verified) ----
        float t0 = rho.x * (d.y - d.x);
        float t1 = rho.y * (d.z - d.y);
        float t2 = rho.z * (d.w - d.z);
        float t3 = rho.w * ((sl == 31) ? FAR_DELTA : (nx - d.w));
        float q1 = t0, q2 = q1 + t1, q3 = q2 + t2, tot = q3 + t3;

        // ---- 32-lane segmented exclusive scan, pure DPP ----
        float incl = tot;
        incl += dpp_f<ROW_SHR(1), 0xF, true>(incl);
        incl += dpp_f<ROW_SHR(2), 0xF, true>(incl);
        incl += dpp_f<ROW_SHR(4), 0xF, true>(incl);
        incl += dpp_f<ROW_SHR(8), 0xF, true>(incl);
        float e = dpp_f<ROW_SHR(1), 0xF, true>(incl);   // row-exclusive
        e += dpp_f<ROW_BCAST15, 0xA, false>(incl);      // + prev row's total

        float T0 = __expf(-e);
        float T1 = __expf(-(e + q1));
        float T2 = __expf(-(e + q2));
        float T3 = __expf(-(e + q3));
        float T4 = __expf(-(e + tot));        // sl==31: exp(-1e10*rho) -> 0
        float w0 = T0 - T1, w1 = T1 - T2, w2 = T2 - T3, w3 = T3 - T4;

        float a3 = w0 * d.x  + w1 * d.y  + w2 * d.z  + w3 * d.w;
        float a0 = w0 * f0.x + w1 * f0.w + w2 * f1.z + w3 * f2.y;
        float a1 = w0 * f0.y + w1 * f1.x + w2 * f1.w + w3 * f2.z;
        float a2 = w0 * f0.z + w1 * f1.y + w2 * f2.x + w3 * f2.w;

        // ---- segment reduction: DPP row tree + one ds_swizzle xor:16 ----
#define RED(a_)                                                               \
    do {                                                                      \
        a_ += dpp_f<ROW_SHL(8), 0xF, true>(a_);                               \
        a_ += dpp_f<ROW_SHL(4), 0xF, true>(a_);                               \
        a_ += dpp_f<ROW_SHL(2), 0xF, true>(a_);                               \
        a_ += dpp_f<ROW_SHL(1), 0xF, true>(a_);                               \
        a_ += __builtin_bit_cast(float,                                       \
            __builtin_amdgcn_ds_swizzle(__builtin_bit_cast(int, a_), 0x401F));\
    } while (0)
        RED(a0); RED(a1); RED(a2); RED(a3);
#undef RED

        if (sl == 0) {
            int ray = 2 * (p * NWAVES + g) + (lane >> 5);
            *(float4*)(out + (size_t)ray * 4) = make_float4(a0, a1, a2, a3);
        }

        // rotate pipeline (SSA-renamed under full unroll; no copies)
        d = pd; rho = pr; f0 = pf0; f1 = pf1; f2 = pf2; nx = pnx;
    }
#undef ISSUE
#undef GLD4
#undef GLD1
}

extern "C" void kernel_launch(void* const* d_in, const int* in_sizes, int n_in,
                              void* d_out, int out_size, void* d_ws, size_t ws_size,
                              hipStream_t stream) {
    const float* depth   = (const float*)d_in[0];
    const float* density = (const float*)d_in[1];
    const float* feature = (const float*)d_in[2];
    float* out = (float*)d_out;

    dim3 grid(NBLOCKS);
    dim3 block(BLOCK);
    volrend_kernel<<<grid, block, 0, stream>>>(depth, density, feature, out);
}

// Round 7
// 192.822 us; speedup vs baseline: 1.0195x; 1.0195x over previous
//
#include <hip/hip_runtime.h>

#define N_RAYS 65536
#define N_PTS  128
#define FAR_DELTA 1e10f

#define BLOCK   256
#define NBLOCKS 2048                          // 8 blocks/CU, no LDS
#define NWAVES  (NBLOCKS * (BLOCK / 64))      // 8192 waves
#define NPAIRS  (N_RAYS / 2)                  // 32768 ray-pairs
#define NP      (NPAIRS / NWAVES)             // 4 pairs per wave

typedef float f32x4 __attribute__((ext_vector_type(4)));

// DPP cross-lane on the VALU pipe (round-5/6 verified math).
#define ROW_SHR(n)  (0x110 | (n))
#define ROW_SHL(n)  (0x100 | (n))
#define ROW_BCAST15 0x142

template<int CTRL, int RMASK, bool BC>
__device__ __forceinline__ float dpp_f(float x) {
    return __builtin_bit_cast(float,
        __builtin_amdgcn_update_dpp(0, __builtin_bit_cast(int, x),
                                    CTRL, RMASK, 0xF, BC));
}

// Round 6 kernel with ONE variable changed: all global loads carry sc0
// (device-coherent -> L1 bypass, served from L2). Tests the hypothesis that
// the per-CU L1 line-fill/tag pipeline is the ~4.2 B/cy/CU read-return
// serializer that has pinned every structure at ~64 us. Layouts, vmcnt
// ledger, scan/reduce math are byte-identical to the verified round 6.
__global__ __launch_bounds__(BLOCK) void volrend_kernel(
    const float* __restrict__ depth,
    const float* __restrict__ density,
    const float* __restrict__ feature,
    float* __restrict__ out)
{
    const int lane = threadIdx.x & 63;
    const int sl   = lane & 31;               // lane within 32-lane ray segment
    const int g    = (int)blockIdx.x * (BLOCK / 64) + (threadIdx.x >> 6);

    f32x4 d, rho, f0, f1, f2;  float nx;      // current pair
    f32x4 pd, pr, pf0, pf1, pf2; float pnx;   // prefetched next pair

#define GLD4(dst_, gp_) \
    asm volatile("global_load_dwordx4 %0, %1, off sc0" : "=v"(dst_) : "v"(gp_))
#define GLD1(dst_, gp_) \
    asm volatile("global_load_dword %0, %1, off sc0"   : "=v"(dst_) : "v"(gp_))

#define ISSUE(p_, D_, R_, F0_, F1_, F2_, NX_)                                 \
    do {                                                                      \
        const float* dp_ = depth + (size_t)(p_) * 256 + 4 * lane;             \
        GLD4(D_, dp_);                                                        \
        GLD1(NX_, dp_ + ((sl == 31) ? 3 : 4));                                \
        GLD4(R_, density + (size_t)(p_) * 256 + 4 * lane);                    \
        const float* fp_ = feature + (size_t)(p_) * 768 + 12 * lane;          \
        GLD4(F0_, fp_);                                                       \
        GLD4(F1_, fp_ + 4);                                                   \
        GLD4(F2_, fp_ + 8);                                                   \
    } while (0)

    ISSUE(g, d, rho, f0, f1, f2, nx);

#pragma unroll
    for (int p = 0; p < NP; ++p) {
        if (p + 1 < NP)
            ISSUE((p + 1) * NWAVES + g, pd, pr, pf0, pf1, pf2, pnx);

        // vmcnt ledger (6 loads L, 1 store S per pair, issue order) --
        // identical to round 6 (verified passing):
        if      (p == 0)      asm volatile("s_waitcnt vmcnt(6)" ::: "memory");
        else if (p <  NP - 1) asm volatile("s_waitcnt vmcnt(7)" ::: "memory");
        else                  asm volatile("s_waitcnt vmcnt(1)" ::: "memory");
        __builtin_amdgcn_sched_barrier(0);

        // ---- taus + in-register local prefix ----
        float t0 = rho.x * (d.y - d.x);
        float t1 = rho.y * (d.z - d.y);
        float t2 = rho.z * (d.w - d.z);
        float t3 = rho.w * ((sl == 31) ? FAR_DELTA : (nx - d.w));
        float q1 = t0, q2 = q1 + t1, q3 = q2 + t2, tot = q3 + t3;

        // ---- 32-lane segmented exclusive scan, pure DPP ----
        float incl = tot;
        incl += dpp_f<ROW_SHR(1), 0xF, true>(incl);
        incl += dpp_f<ROW_SHR(2), 0xF, true>(incl);
        incl += dpp_f<ROW_SHR(4), 0xF, true>(incl);
        incl += dpp_f<ROW_SHR(8), 0xF, true>(incl);
        float e = dpp_f<ROW_SHR(1), 0xF, true>(incl);   // row-exclusive
        e += dpp_f<ROW_BCAST15, 0xA, false>(incl);      // + prev row's total

        float T0 = __expf(-e);
        float T1 = __expf(-(e + q1));
        float T2 = __expf(-(e + q2));
        float T3 = __expf(-(e + q3));
        float T4 = __expf(-(e + tot));        // sl==31: exp(-1e10*rho) -> 0
        float w0 = T0 - T1, w1 = T1 - T2, w2 = T2 - T3, w3 = T3 - T4;

        float a3 = w0 * d.x  + w1 * d.y  + w2 * d.z  + w3 * d.w;
        float a0 = w0 * f0.x + w1 * f0.w + w2 * f1.z + w3 * f2.y;
        float a1 = w0 * f0.y + w1 * f1.x + w2 * f1.w + w3 * f2.z;
        float a2 = w0 * f0.z + w1 * f1.y + w2 * f2.x + w3 * f2.w;

        // ---- segment reduction: DPP row tree + one ds_swizzle xor:16 ----
#define RED(a_)                                                               \
    do {                                                                      \
        a_ += dpp_f<ROW_SHL(8), 0xF, true>(a_);                               \
        a_ += dpp_f<ROW_SHL(4), 0xF, true>(a_);                               \
        a_ += dpp_f<ROW_SHL(2), 0xF, true>(a_);                               \
        a_ += dpp_f<ROW_SHL(1), 0xF, true>(a_);                               \
        a_ += __builtin_bit_cast(float,                                       \
            __builtin_amdgcn_ds_swizzle(__builtin_bit_cast(int, a_), 0x401F));\
    } while (0)
        RED(a0); RED(a1); RED(a2); RED(a3);
#undef RED

        if (sl == 0) {
            int ray = 2 * (p * NWAVES + g) + (lane >> 5);
            *(float4*)(out + (size_t)ray * 4) = make_float4(a0, a1, a2, a3);
        }

        // rotate pipeline
        d = pd; rho = pr; f0 = pf0; f1 = pf1; f2 = pf2; nx = pnx;
    }
#undef ISSUE
#undef GLD4
#undef GLD1
}

extern "C" void kernel_launch(void* const* d_in, const int* in_sizes, int n_in,
                              void* d_out, int out_size, void* d_ws, size_t ws_size,
                              hipStream_t stream) {
    const float* depth   = (const float*)d_in[0];
    const float* density = (const float*)d_in[1];
    const float* feature = (const float*)d_in[2];
    float* out = (float*)d_out;

    dim3 grid(NBLOCKS);
    dim3 block(BLOCK);
    volrend_kernel<<<grid, block, 0, stream>>>(depth, density, feature, out);
}